// Round 2
// baseline (108.093 us; speedup 1.0000x reference)
//
#include <hip/hip_runtime.h>

// Problem constants (match reference)
#define S    2048
#define H    16
#define BH   32
#define ROWS 32          // rows of the S x S matrix per block
#define TPB  256
#define TILES_PER_H (S / ROWS)   // 64

typedef float f32x4 __attribute__((ext_vector_type(4)));

// out[bh, i, j] = e1[i-j, h] if i>=j else e2[j-i-1, h],  h = bh % 16,
// identical for bh and bh+16.  Per head h define
//   M[u] = e1[u-(S-1), h]   for u >= S-1
//        = e2[(S-2)-u, h]   for u <  S-1        (u in [0, 2S-2])
// then out[i, j] = M[i - j + (S-1)].
__global__ __launch_bounds__(TPB) void relpos_kernel(
    const float* __restrict__ e1,   // (S, H)
    const float* __restrict__ e2,   // (S-1, H)
    float* __restrict__ out)        // (BH, S, S)
{
    __shared__ float M[2 * S];      // use [0 .. 2S-2]

    const int tile = blockIdx.x & (TILES_PER_H - 1);
    const int h    = blockIdx.x >> 6;           // / TILES_PER_H
    const int tid  = threadIdx.x;

    // Stage merged bias vector for this head into LDS.
    for (int u = tid; u < 2 * S - 1; u += TPB) {
        float v;
        if (u >= S - 1) v = e1[(u - (S - 1)) * H + h];
        else            v = e2[((S - 2) - u) * H + h];
        M[u] = v;
    }
    __syncthreads();

    const int ibase = tile * ROWS;
    float* out0 = out + (size_t)h * S * S;            // batch 0 copy
    float* out1 = out + (size_t)(h + H) * S * S;      // batch 1 copy

    for (int r = 0; r < ROWS; ++r) {
        const int i = ibase + r;
        const size_t rowoff = (size_t)i * S;
        #pragma unroll
        for (int k = 0; k < S / (TPB * 4); ++k) {     // 2 iterations
            const int j  = (tid + k * TPB) * 4;
            const int u0 = i - j + (S - 1);           // in [3, 2S-2]
            f32x4 v;
            v.x = M[u0];
            v.y = M[u0 - 1];
            v.z = M[u0 - 2];
            v.w = M[u0 - 3];
            __builtin_nontemporal_store(v, (f32x4*)(out0 + rowoff + j));
            __builtin_nontemporal_store(v, (f32x4*)(out1 + rowoff + j));
        }
    }
}

extern "C" void kernel_launch(void* const* d_in, const int* in_sizes, int n_in,
                              void* d_out, int out_size, void* d_ws, size_t ws_size,
                              hipStream_t stream) {
    // inputs: d_in[0] = q (unused), d_in[1] = e1 (S*H), d_in[2] = e2 ((S-1)*H)
    const float* e1 = (const float*)d_in[1];
    const float* e2 = (const float*)d_in[2];
    float* out = (float*)d_out;

    const int grid = H * TILES_PER_H;   // 1024 blocks
    relpos_kernel<<<grid, TPB, 0, stream>>>(e1, e2, out);
}

// Round 3
// 107.368 us; speedup vs baseline: 1.0068x; 1.0068x over previous
//
#include <hip/hip_runtime.h>

// Problem constants (match reference)
#define S    2048
#define H    16
#define ROWS 32          // rows of the S x S matrix per block
#define TPB  256
#define TILES_PER_H (S / ROWS)   // 64

typedef float f32x4 __attribute__((ext_vector_type(4)));

// out[bh, i, j] = e1[i-j, h] if i>=j else e2[j-i-1, h],  h = bh % 16,
// identical for bh and bh+16.  Store the REVERSED merged bias vector:
//   R[v] = e1[S-1-v, h]  for v <= S-1
//        = e2[v-S,   h]  for v >  S-1        (v in [0, 2S-2])
// then out[i, j] = R[(S-1) - i + j]  -> row i reads R FORWARD from (S-1-i).
__global__ __launch_bounds__(TPB) void relpos_kernel(
    const float* __restrict__ e1,   // (S, H)
    const float* __restrict__ e2,   // (S-1, H)
    float* __restrict__ out)        // (2H, S, S)
{
    __shared__ __align__(16) float R[2 * S];

    const int tile = blockIdx.x & (TILES_PER_H - 1);
    const int h    = blockIdx.x >> 6;           // / TILES_PER_H
    const int tid  = threadIdx.x;

    for (int v = tid; v < 2 * S - 1; v += TPB) {
        float val;
        if (v <= S - 1) val = e1[(S - 1 - v) * H + h];
        else            val = e2[(v - S) * H + h];
        R[v] = val;
    }
    __syncthreads();

    const int ibase = tile * ROWS;
    float* const out0 = out + (size_t)h * S * S + (size_t)ibase * S; // batch 0
    float* const out1 = out0 + (size_t)H * S * S;                    // batch 1

    // Per column block: thread covers columns j0..j0+3 for 32 rows.
    // Needed R values: R[wbase .. wbase+34], wbase = (S-1-ibase)+j0-31
    // (4-aligned since ibase%4==0, j0%4==0). Load once into registers,
    // then every row's float4 is statically indexed (no scratch).
    #pragma unroll
    for (int k = 0; k < 2; ++k) {
        const int j0    = (tid + k * TPB) * 4;
        const int wbase = (S - 1 - ibase) + j0 - 31;
        f32x4 w4[9];
        #pragma unroll
        for (int c = 0; c < 9; ++c)
            w4[c] = *(const f32x4*)&R[wbase + 4 * c];
#define W(t) w4[(t) >> 2][(t) & 3]
        #pragma unroll
        for (int r = 0; r < ROWS; ++r) {
            f32x4 v;
            v.x = W(31 - r);
            v.y = W(32 - r);
            v.z = W(33 - r);
            v.w = W(34 - r);
            *(f32x4*)(out0 + (size_t)r * S + j0) = v;
            *(f32x4*)(out1 + (size_t)r * S + j0) = v;
        }
#undef W
    }
}

extern "C" void kernel_launch(void* const* d_in, const int* in_sizes, int n_in,
                              void* d_out, int out_size, void* d_ws, size_t ws_size,
                              hipStream_t stream) {
    // inputs: d_in[0] = q (unused), d_in[1] = e1 (S*H), d_in[2] = e2 ((S-1)*H)
    const float* e1 = (const float*)d_in[1];
    const float* e2 = (const float*)d_in[2];
    float* out = (float*)d_out;

    const int grid = H * TILES_PER_H;   // 1024 blocks
    relpos_kernel<<<grid, TPB, 0, stream>>>(e1, e2, out);
}

// Round 4
// 105.684 us; speedup vs baseline: 1.0228x; 1.0159x over previous
//
#include <hip/hip_runtime.h>

// Problem constants (match reference)
#define S    2048
#define H    16
#define ROWS 32                  // rows per block
#define TPB  256
#define TILES_PER_H (S / ROWS)   // 64
#define MSTRIDE 4096             // padded length of per-head merged vector

typedef float f32x4 __attribute__((ext_vector_type(4)));

// out[bh, i, j] = e1[i-j, h] if i>=j else e2[j-i-1, h],  h = bh % 16.
// Reversed merged vector per head:
//   M[h][v] = e1[S-1-v, h]  for v <= S-1
//           = e2[v-S,   h]  for S <= v <= 2S-2
// then out[i, j] = M[h][(S-1) - i + j]  (row i reads M forward from S-1-i).

// Prep: transpose e1/e2 head-columns into contiguous per-head vectors in ws.
__global__ __launch_bounds__(TPB) void relpos_prep(
    const float* __restrict__ e1,   // (S, H)
    const float* __restrict__ e2,   // (S-1, H)
    float* __restrict__ M)          // (H, MSTRIDE)
{
    const int h = blockIdx.x;
    float* Mh = M + (size_t)h * MSTRIDE;
    for (int v = threadIdx.x; v < MSTRIDE; v += TPB) {
        float val = 0.0f;
        if (v <= S - 1)          val = e1[(S - 1 - v) * H + h];
        else if (v <= 2 * S - 2) val = e2[(v - S) * H + h];
        Mh[v] = val;
    }
}

// Main: pure store stream. No LDS, no syncthreads.
__global__ __launch_bounds__(TPB) void relpos_main(
    const float* __restrict__ M,    // (H, MSTRIDE) in ws
    float* __restrict__ out)        // (2H, S, S)
{
    const int tile = blockIdx.x & (TILES_PER_H - 1);
    const int bh   = blockIdx.x >> 6;          // 0..31
    const int h    = bh & (H - 1);
    const int tid  = threadIdx.x;

    const int ibase = tile * ROWS;
    const float* Mh = M + (size_t)h * MSTRIDE;
    float* const o  = out + (size_t)bh * S * S + (size_t)ibase * S;

    #pragma unroll
    for (int k = 0; k < 2; ++k) {
        const int j0    = (tid + k * TPB) * 4;
        const int wbase = (S - 1 - ibase) + j0 - 31;   // 4-aligned, in [0, 4060]
        f32x4 w4[9];
        #pragma unroll
        for (int c = 0; c < 9; ++c)
            w4[c] = *(const f32x4*)&Mh[wbase + 4 * c];
#define W(t) w4[(t) >> 2][(t) & 3]
        #pragma unroll
        for (int r = 0; r < ROWS; ++r) {
            f32x4 v;
            v.x = W(31 - r);
            v.y = W(32 - r);
            v.z = W(33 - r);
            v.w = W(34 - r);
            *(f32x4*)(o + (size_t)r * S + j0) = v;
        }
#undef W
    }
}

extern "C" void kernel_launch(void* const* d_in, const int* in_sizes, int n_in,
                              void* d_out, int out_size, void* d_ws, size_t ws_size,
                              hipStream_t stream) {
    // inputs: d_in[0] = q (unused), d_in[1] = e1 (S*H), d_in[2] = e2 ((S-1)*H)
    const float* e1 = (const float*)d_in[1];
    const float* e2 = (const float*)d_in[2];
    float* out = (float*)d_out;
    float* M   = (float*)d_ws;     // needs H*MSTRIDE*4 = 256 KiB

    relpos_prep<<<H, TPB, 0, stream>>>(e1, e2, M);
    relpos_main<<<2 * H * TILES_PER_H, TPB, 0, stream>>>(M, out);
}

// Round 5
// 98.501 us; speedup vs baseline: 1.0974x; 1.0729x over previous
//
#include <hip/hip_runtime.h>

// Problem constants (match reference)
#define S    2048
#define H    16
#define ROWS 32                  // rows per block
#define TPB  256
#define TILES_PER_H (S / ROWS)   // 64
#define MSTRIDE 4096             // padded length of per-head merged vector
#define PREP_SPLIT 4             // blocks per head in prep

typedef float f32x4 __attribute__((ext_vector_type(4)));

// out[bh, i, j] = e1[i-j, h] if i>=j else e2[j-i-1, h],  h = bh % 16.
// Reversed merged vector per head:
//   M[h][v] = e1[S-1-v, h]  for v <= S-1
//           = e2[v-S,   h]  for S <= v <= 2S-2, else 0
// then out[i, j] = M[h][(S-1) - i + j]  (row i reads M forward from S-1-i).

// Prep: 64 blocks (4 per head) for gather parallelism; latency-bound.
__global__ __launch_bounds__(TPB) void relpos_prep(
    const float* __restrict__ e1,   // (S, H)
    const float* __restrict__ e2,   // (S-1, H)
    float* __restrict__ M)          // (H, MSTRIDE)
{
    const int h    = blockIdx.x >> 2;            // / PREP_SPLIT
    const int part = blockIdx.x & (PREP_SPLIT - 1);
    float* Mh = M + (size_t)h * MSTRIDE;
    const int v0 = part * (MSTRIDE / PREP_SPLIT);
    const int v1 = v0 + (MSTRIDE / PREP_SPLIT);
    for (int v = v0 + (int)threadIdx.x; v < v1; v += TPB) {
        float val = 0.0f;
        if (v <= S - 1)          val = e1[(S - 1 - v) * H + h];
        else if (v <= 2 * S - 2) val = e2[(v - S) * H + h];
        Mh[v] = val;
    }
}

// Main: pure store stream, strictly monotone contiguous 256 KiB per block.
__global__ __launch_bounds__(TPB) void relpos_main(
    const float* __restrict__ M,    // (H, MSTRIDE) in ws
    float* __restrict__ out)        // (2H, S, S)
{
    const int tile = blockIdx.x & (TILES_PER_H - 1);
    const int bh   = blockIdx.x >> 6;            // 0..31
    const int h    = bh & (H - 1);
    const int tid  = threadIdx.x;

    const int ibase = tile * ROWS;
    const float* Mh = M + (size_t)h * MSTRIDE;
    float* const o  = out + (size_t)bh * S * S + (size_t)ibase * S;

    // Preload BOTH column-half windows (statically indexed -> registers).
    const int j0  = tid * 4;
    const int wb0 = (S - 1 - ibase) + j0 - 31;   // 4-aligned, in [0, 3036]
    f32x4 w4[18];
    #pragma unroll
    for (int c = 0; c < 9; ++c) w4[c]     = *(const f32x4*)&Mh[wb0 + 4 * c];
    #pragma unroll
    for (int c = 0; c < 9; ++c) w4[9 + c] = *(const f32x4*)&Mh[wb0 + 1024 + 4 * c];
#define W0(t) w4[(t) >> 2][(t) & 3]
#define W1(t) w4[9 + ((t) >> 2)][(t) & 3]
    // r-outer: block writes rows in order; within a row, k=0 columns then
    // k=1 columns -> one monotone contiguous stream.
    #pragma unroll
    for (int r = 0; r < ROWS; ++r) {
        f32x4 a, b;
        a.x = W0(31 - r); a.y = W0(32 - r); a.z = W0(33 - r); a.w = W0(34 - r);
        b.x = W1(31 - r); b.y = W1(32 - r); b.z = W1(33 - r); b.w = W1(34 - r);
        *(f32x4*)(o + (size_t)r * S + j0)        = a;
        *(f32x4*)(o + (size_t)r * S + j0 + 1024) = b;
    }
#undef W0
#undef W1
}

extern "C" void kernel_launch(void* const* d_in, const int* in_sizes, int n_in,
                              void* d_out, int out_size, void* d_ws, size_t ws_size,
                              hipStream_t stream) {
    // inputs: d_in[0] = q (unused), d_in[1] = e1 (S*H), d_in[2] = e2 ((S-1)*H)
    const float* e1 = (const float*)d_in[1];
    const float* e2 = (const float*)d_in[2];
    float* out = (float*)d_out;
    float* M   = (float*)d_ws;     // needs H*MSTRIDE*4 = 256 KiB

    relpos_prep<<<H * PREP_SPLIT, TPB, 0, stream>>>(e1, e2, M);
    relpos_main<<<2 * H * TILES_PER_H, TPB, 0, stream>>>(M, out);
}